// Round 3
// baseline (5475.403 us; speedup 1.0000x reference)
//
#include <hip/hip_runtime.h>
#include <math.h>

// Problem constants (fixed by reference setup_inputs)
#define RS 3072   // B*CH signals
#define NF 2048   // signal length N
#define MS 512    // measurements M

typedef _Float16 f16;
typedef _Float16 f16x4 __attribute__((ext_vector_type(4)));
typedef _Float16 f16x8 __attribute__((ext_vector_type(8)));
typedef float f32x4 __attribute__((ext_vector_type(4)));

// idxs may be delivered as int64 (little-endian pairs [lo,0]) or int32.
// Sorted-unique indices => idxs[1] >= 1, so p[1]==0 iff int64 layout.
__device__ __forceinline__ int load_idx(const int* p, int j) {
    return (p[1] == 0) ? p[2 * j] : p[j];
}

#define PI_OVER_4096 7.669903939428206e-4f
#define CK0 0.022097086912079608f  // sqrt(1/2048)
#define CKN 0.03125f               // sqrt(2/2048)

// Wg[j][k] = A[j,k] = c_k cos(pi*(2*idxs[j]+1)*k/4096)   (512 x 2048, k-contig)
// Wh[k][j] = A[j,k]                                       (2048 x 512, j-contig)
__global__ void build_w_kernel(const int* idxs, f16* Wg, f16* Wh) {
    int t = blockIdx.x * 256 + threadIdx.x;   // over MS*NF
    int j = t >> 11, k = t & (NF - 1);
    int ii = load_idx(idxs, j);
    float ck = (k == 0) ? CK0 : CKN;
    int ph = ((2 * ii + 1) * k) & 8191;
    float v = ck * cosf((float)ph * PI_OVER_4096);
    Wg[(size_t)j * NF + k] = (f16)v;
    Wh[(size_t)k * MS + j] = (f16)v;
}

// Dg[i][k] = IDCT[i,k] = c_k cos(pi*(2i+1)k/4096)  (2048 x 2048, k-contig)
__global__ void build_d_kernel(f16* Dg) {
    int t = blockIdx.x * 256 + threadIdx.x;   // over NF*NF
    int i = t >> 11, k = t & (NF - 1);
    float ck = (k == 0) ? CK0 : CKN;
    int ph = ((2 * i + 1) * k) & 8191;
    Dg[(size_t)i * NF + k] = (f16)(ck * cosf((float)ph * PI_OVER_4096));
}

// Bm[r][j] = x[r, idxs[j]]  (UNSCALED; e = 100*acc in epilogue)
__global__ void build_b_kernel(const float* x, const int* idxs, f16* Bm) {
    int t = blockIdx.x * 256 + threadIdx.x;   // over RS*MS
    int r = t >> 9, j = t & (MS - 1);
    Bm[t] = (f16)(x[(size_t)r * NF + load_idx(idxs, j)]);
}

__device__ __forceinline__ void async_copy16(const void* g, void* l) {
    __builtin_amdgcn_global_load_lds(
        (__attribute__((address_space(1))) const void*)g,
        (__attribute__((address_space(3))) void*)l, 16, 0, 0);
}

// H = clamp(20*e, -1, 1) in f16 — single shared definition so the H written
// to the buffer (GEMM1's operand) and the epilogue recompute round identically.
__device__ __forceinline__ f16 hclamp(f16 e) {
    f16 s = (f16)(e * (f16)20.0);
    s = s > (f16)1.0 ? (f16)1.0 : s;
    s = s < (f16)-1.0 ? (f16)-1.0 : s;
    return s;
}

// GEMM: acc[u][r] = sum_k A[u][k] * B[r][k]; both operands async-staged.
// Output-contiguous dim = u (MFMA M axis) => f16x4 / f32x4 vector stores.
// Block decode (GRP=0): xcd = blk&7 gets r-panels [xcd*RPX, xcd*RPX+RPX) x all
// NP u-panels => per-XCD L2 holds the full A panel set + RPX B strips.
// (GRP=1): xcd gets u-panels xcd*NP..+NP-1 x all r-panels (final GEMM: A=Dg
// strips stay L2-resident, B=e' streams once per XCD).
// MODE 0: e = 100*acc; H = hclamp(e)       (c-build, A=Wh, B=Bm)
// MODE 1: Y = acc                          (GEMM1, A=Wg, B=H)
// MODE 2: e += 0.05*(acc - hclamp(e_old)); H = hclamp(e_new)   (A=Wh, B=Y)
// MODE 3: MODE2 but write e' = e_new - 0.05*hclamp(e_new), no H
// MODE 4: out = 0.01*acc                   (final idct, A=Dg, B=e')
template<int BU, int BR, int NP, int RPX, int GRP, int MODE>
__global__ __launch_bounds__(256) void gemm_k(
    const f16* __restrict__ A, const f16* __restrict__ B,
    const f16* __restrict__ eb, f16* __restrict__ hb,
    f16* __restrict__ o16, float* __restrict__ outF, int K, int ldo)
{
    constexpr int WU = BU / 2, WR = BR / 2;   // 4 waves, 2x2
    constexpr int IM = WU / 16, IN = WR / 16;
    constexpr int LNP = (NP == 2) ? 1 : (NP == 4) ? 2 : (NP == 8) ? 3 : 4;
    __shared__ __align__(16) f16 As[BU * 32];
    __shared__ __align__(16) f16 Bs[BR * 32];

    const int tid = threadIdx.x;
    const int w = tid >> 6, l = tid & 63;
    const int wr = w >> 1, wc = w & 1;
    const int q = l >> 4, ln = l & 15;
    const int lrow = l >> 2, lk8 = (l & 3) * 8;

    const int blk = blockIdx.x, xcd = blk & 7, local = blk >> 3;
    int up, rp;
    if constexpr (GRP == 0) { up = local & (NP - 1); rp = xcd * RPX + (local >> LNP); }
    else                    { up = xcd * NP + (local & (NP - 1)); rp = local >> LNP; }
    const int bu = up * BU, br = rp * BR;

    f32x4 acc[IM][IN];
#pragma unroll
    for (int a = 0; a < IM; ++a)
#pragma unroll
        for (int b = 0; b < IN; ++b)
            acc[a][b] = (f32x4){0.f, 0.f, 0.f, 0.f};

    const f16* Ab = A + (size_t)bu * K + lk8;
    const f16* Bb = B + (size_t)br * K + lk8;

    for (int k0 = 0; k0 < K; k0 += 32) {
#pragma unroll
        for (int i = 0; i < BU / 64; ++i)
            async_copy16(Ab + (size_t)(i * 64 + w * 16 + lrow) * K + k0,
                         As + i * 2048 + w * 512 + l * 8);
#pragma unroll
        for (int i = 0; i < BR / 64; ++i)
            async_copy16(Bb + (size_t)(i * 64 + w * 16 + lrow) * K + k0,
                         Bs + i * 2048 + w * 512 + l * 8);
        __syncthreads();

        f16x8 af[IM], bf[IN];
#pragma unroll
        for (int im = 0; im < IM; ++im)
            af[im] = *(const f16x8*)(As + (wr * WU + im * 16 + ln) * 32 + q * 8);
#pragma unroll
        for (int in = 0; in < IN; ++in)
            bf[in] = *(const f16x8*)(Bs + (wc * WR + in * 16 + ln) * 32 + q * 8);
#pragma unroll
        for (int im = 0; im < IM; ++im)
#pragma unroll
            for (int in = 0; in < IN; ++in)
                acc[im][in] = __builtin_amdgcn_mfma_f32_16x16x32_f16(
                    af[im], bf[in], acc[im][in], 0, 0, 0);
        __syncthreads();
    }

    // epilogue: C/D layout col(lane&15)=r-frag, row(q*4+reg)=u-frag (contig)
#pragma unroll
    for (int im = 0; im < IM; ++im) {
#pragma unroll
        for (int in = 0; in < IN; ++in) {
            const int u0 = bu + wr * WU + im * 16 + q * 4;
            const int r0 = br + wc * WR + in * 16 + ln;
            const size_t off = (size_t)r0 * ldo + u0;
            f32x4 a4 = acc[im][in];
            if constexpr (MODE == 0) {
                f16x4 ee, hh;
#pragma unroll
                for (int e = 0; e < 4; ++e) {
                    f16 ev = (f16)(100.0f * a4[e]);
                    ee[e] = ev; hh[e] = hclamp(ev);
                }
                *(f16x4*)(o16 + off) = ee;
                *(f16x4*)(hb + off) = hh;
            } else if constexpr (MODE == 1) {
                f16x4 yy;
#pragma unroll
                for (int e = 0; e < 4; ++e) yy[e] = (f16)a4[e];
                *(f16x4*)(o16 + off) = yy;
            } else if constexpr (MODE == 2 || MODE == 3) {
                f16x4 e4 = *(const f16x4*)(eb + off);
                f16x4 st, hn;
#pragma unroll
                for (int e = 0; e < 4; ++e) {
                    f16 hz = hclamp(e4[e]);                    // == GEMM1's operand
                    float en = (float)e4[e] + 0.05f * (a4[e] - (float)hz);
                    if constexpr (MODE == 2) {
                        f16 ef = (f16)en;
                        st[e] = ef; hn[e] = hclamp(ef);
                    } else {
                        float zf = fminf(fmaxf(20.0f * en, -1.f), 1.f);
                        st[e] = (f16)(en - 0.05f * zf);        // e' = e100 - 0.05*h100
                    }
                }
                *(f16x4*)(o16 + off) = st;
                if constexpr (MODE == 2) *(f16x4*)(hb + off) = hn;
            } else {
                f32x4 ov;
#pragma unroll
                for (int e = 0; e < 4; ++e) ov[e] = 0.01f * a4[e];
                *(f32x4*)(outF + off) = ov;
            }
        }
    }
}

extern "C" void kernel_launch(void* const* d_in, const int* in_sizes, int n_in,
                              void* d_out, int out_size, void* d_ws, size_t ws_size,
                              hipStream_t stream) {
    const float* x = (const float*)d_in[0];
    const int* idxs = (const int*)d_in[1];

    // Workspace: 2+2+3+12.6+12.6 = 32.8 MB (< round-1's proven-safe 35.2 MB).
    // Dg (8 MB) aliases H16 — H is dead after the last MODE-1 GEMM.
    char* p = (char*)d_ws;
    auto take = [&](size_t n) { char* q = p; p += (n + 255) & ~(size_t)255; return q; };
    f16* Wg  = (f16*)take((size_t)MS * NF * 2);   // 2 MB   A row-major (j,k)
    f16* Wh  = (f16*)take((size_t)NF * MS * 2);   // 2 MB   A^T row-major (n,j)
    f16* BmY = (f16*)take((size_t)RS * MS * 2);   // 3 MB   Bm, then Y
    f16* e16 = (f16*)take((size_t)RS * NF * 2);   // 12.6 MB  e = v + c (then e')
    f16* H16 = (f16*)take((size_t)RS * NF * 2);   // 12.6 MB  H = clip(20e)
    f16* Dg  = H16;                               // 8 MB   idct matrix (aliased)

    build_w_kernel<<<dim3(MS * NF / 256), 256, 0, stream>>>(idxs, Wg, Wh);
    build_b_kernel<<<dim3(RS * MS / 256), 256, 0, stream>>>(x, idxs, BmY);

    // e0 = c = 100 * Bm @ A ;  H1 = clip(20*e0)
    gemm_k<128, 64, 16, 6, 0, 0><<<dim3(768), 256, 0, stream>>>(
        Wh, BmY, nullptr, H16, e16, nullptr, MS, NF);

    // 99 iterations: Y = Wg @ H ;  e += 0.05*(Wh @ Y - H), H = clip(20e)
    for (int it = 0; it < 99; ++it) {
        gemm_k<128, 64, 4, 6, 0, 1><<<dim3(192), 256, 0, stream>>>(
            Wg, H16, nullptr, nullptr, BmY, nullptr, NF, MS);
        if (it < 98)
            gemm_k<128, 64, 16, 6, 0, 2><<<dim3(768), 256, 0, stream>>>(
                Wh, BmY, e16, H16, e16, nullptr, MS, NF);
        else
            gemm_k<128, 64, 16, 6, 0, 3><<<dim3(768), 256, 0, stream>>>(
                Wh, BmY, e16, nullptr, e16, nullptr, MS, NF);
    }

    // out = 0.01 * e' @ D   (msk*x cancels against c@D analytically)
    build_d_kernel<<<dim3(NF * NF / 256), 256, 0, stream>>>(Dg);
    gemm_k<128, 64, 2, 48, 1, 4><<<dim3(768), 256, 0, stream>>>(
        Dg, e16, nullptr, nullptr, nullptr, (float*)d_out, NF, NF);
}